// Round 1
// baseline (6560.937 us; speedup 1.0000x reference)
//
#include <hip/hip_runtime.h>
#include <cstdint>
#include <cstddef>

typedef unsigned short u16;
typedef unsigned int u32;
typedef __attribute__((ext_vector_type(8))) short short8;
typedef __attribute__((ext_vector_type(4))) float f32x4;

#define AGENT_SCOPE __HIP_MEMORY_SCOPE_AGENT
#define SPIN_CAP 20000000
#define POLL_CAP 200000
#define SENT 0xFFFFFFFFu

__device__ __forceinline__ u16 f2bf(float f) {
  u32 u = __float_as_uint(f);
  return (u16)((u + 0x7FFFu + ((u >> 16) & 1u)) >> 16);
}
__device__ __forceinline__ float bf2f(u16 s) { return __uint_as_float(((u32)s) << 16); }
__device__ __forceinline__ float sigm(float x) { return 1.f / (1.f + __expf(-x)); }
__device__ __forceinline__ float tanha(float x) { return 1.f - 2.f / (__expf(2.f * x) + 1.f); }
__device__ __forceinline__ void wait_vm0() { asm volatile("s_waitcnt vmcnt(0)" ::: "memory"); }

// Barrier-free persistent LSTM autoencoder.
// 256 WGs x 256 thr: col = bid&3 (16 batches), rowg = bid>>2 in [0,64) (8 hidden
// units = 32 gate rows). h exchange via depth-3 LLC ring, bf16 pairs packed in
// dwords; consumers poll the DATA dwords (agent relaxed loads) until != SENT;
// producers SENT-clear the buffer reused at slot s+1.
// This round: (a) encoder x-loads issued BEFORE the poll, converted after
// (overlap HBM/LLC latency with the poll round); (b) decoder recon folded into
// 16 MFMAs on wave 0 (opW B-frags in VGPRs, direct lane stores) — removes the
// scalar 128-product VALU loop, the sP round-trip, and BOTH extra barriers.
__global__ void __launch_bounds__(256, 1)
lstm_ae_kernel(const float* __restrict__ x,
    const float* __restrict__ eWih0, const float* __restrict__ eWhh0,
    const float* __restrict__ ebi0,  const float* __restrict__ ebh0,
    const float* __restrict__ eWih1, const float* __restrict__ eWhh1,
    const float* __restrict__ ebi1,  const float* __restrict__ ebh1,
    const float* __restrict__ dWhh0,
    const float* __restrict__ dbi0,  const float* __restrict__ dbh0,
    const float* __restrict__ dWih1, const float* __restrict__ dWhh1,
    const float* __restrict__ dbi1,  const float* __restrict__ dbh1,
    const float* __restrict__ tlW,   const float* __restrict__ tlb,
    const float* __restrict__ lhW,   const float* __restrict__ lhb,
    const float* __restrict__ opW,   const float* __restrict__ opb,
    float* __restrict__ out, char* __restrict__ wsb)
{
  __shared__ __align__(16) u16 sH0[16 * 520];   // staged h0 bf16, row stride 520
  __shared__ __align__(16) u16 sH1[16 * 520];
  __shared__ __align__(16) u16 sX[16 * 136];
  __shared__ float sP[4 * 256];                  // per-wave MFMA partials [16b][16n]
  __shared__ float sBias[64];                    // [2 layer][32 gate-rows]
  __shared__ float sC[256];                      // [2][16 b][8 u] cell state fp32
  __shared__ float sZ[16 * 64];
  __shared__ float sOPB[4];

  u32* gcnt  = (u32*)wsb;
  float* zbuf= (float*)(wsb + 4096);             // [64][64]
  u32* h0r   = (u32*)(wsb + 32768);              // [3 q][4 col][64 rowg][64 dw]
  u32* h1r   = (u32*)(wsb + 229376);             // same (196608 B each)

  const int tid  = threadIdx.x;
  const int col  = blockIdx.x & 3;
  const int rowg = blockIdx.x >> 2;              // 0..63
  const int wid  = tid >> 6;
  const int lane = tid & 63;
  const int m    = lane & 15;
  const int qo   = (lane >> 4) * 8;

  // ---------- helpers ----------
  // poll+stage one slot's h0 (q0) and optionally h1 (q1) column images into LDS
  auto stage_slot = [&](int q0, int q1, bool p0on, bool p1on) {
    const u32* b0 = h0r + ((q0 * 4 + col) << 12) + tid;
    const u32* b1 = h1r + ((q1 * 4 + col) << 12) + tid;
    u32 v0[16], v1[16];
    int it = 0; bool ok = false;
    while (!ok && it++ < POLL_CAP) {
      ok = true;
      if (p0on) {
        #pragma unroll
        for (int i = 0; i < 16; ++i) {
          v0[i] = __hip_atomic_load(b0 + i * 256, __ATOMIC_RELAXED, AGENT_SCOPE);
          ok &= (v0[i] != SENT);
        }
      }
      if (p1on) {
        #pragma unroll
        for (int i = 0; i < 16; ++i) {
          v1[i] = __hip_atomic_load(b1 + i * 256, __ATOMIC_RELAXED, AGENT_SCOPE);
          ok &= (v1[i] != SENT);
        }
      }
    }
    u32* dH0 = (u32*)sH0; u32* dH1 = (u32*)sH1;
    #pragma unroll
    for (int i = 0; i < 16; ++i) {
      int g = i * 256 + tid;
      int rg = g >> 6, b = (g >> 2) & 15, udw = g & 3;
      if (p0on) dH0[b * 260 + rg * 4 + udw] = v0[i];
      if (p1on) dH1[b * 260 + rg * 4 + udw] = v1[i];
    }
  };

  // SENT-clear own blocks of the buffers reused at slot s+1 (issued during compute;
  // drained by the pre-act __syncthreads, i.e. before this slot's data stores land)
  auto clears = [&](int s) {
    if (tid < 64) {
      int cq0 = (s + 1) % 3, cq1 = s % 3;
      __hip_atomic_store(h0r + ((cq0 * 4 + col) << 12) + (rowg << 6) + tid,
                         SENT, __ATOMIC_RELAXED, AGENT_SCOPE);
      __hip_atomic_store(h1r + ((cq1 * 4 + col) << 12) + (rowg << 6) + tid,
                         SENT, __ATOMIC_RELAXED, AGENT_SCOPE);
    }
  };

  // B-fragment loader: weight row, bf16-converted, k window kofs+qo..+8
  auto ldw = [&](const float* W, int ld, int row, int kofs) -> short8 {
    const float* p = W + (size_t)row * ld + kofs + qo;
    float4 f0 = *(const float4*)p, f1 = *(const float4*)(p + 4);
    short8 r;
    r[0] = (short)f2bf(f0.x); r[1] = (short)f2bf(f0.y);
    r[2] = (short)f2bf(f0.z); r[3] = (short)f2bf(f0.w);
    r[4] = (short)f2bf(f1.x); r[5] = (short)f2bf(f1.y);
    r[6] = (short)f2bf(f1.z); r[7] = (short)f2bf(f1.w);
    return r;
  };

  // gates (R2-verified mapping): L0 slots 0,1; L1 slots 2,3.
  auto act_store = [&](bool L0a, bool L1a, int q0, int q1) {
    int li = tid >> 7, b = (tid >> 3) & 15, u = tid & 7;
    bool actv = li ? L1a : L0a;
    float hv = 0.f;
    if (actv) {
      float gi = sP[(li*2)*256   + b*16 + u]     + sBias[li*32 + u];
      float gf = sP[(li*2)*256   + b*16 + 8 + u] + sBias[li*32 + 8 + u];
      float gg = sP[(li*2+1)*256 + b*16 + u]     + sBias[li*32 + 16 + u];
      float go = sP[(li*2+1)*256 + b*16 + 8 + u] + sBias[li*32 + 24 + u];
      float c = sC[(li*16 + b)*8 + u];
      c = sigm(gf)*c + sigm(gi)*tanha(gg);
      sC[(li*16 + b)*8 + u] = c;
      hv = sigm(go)*tanha(c);
    }
    u16 hb = f2bf(hv);
    u32 other = __shfl_xor((u32)hb, 1);
    if (actv && !(u & 1)) {
      u32 v = (u32)hb | (other << 16);
      u32* ring = li ? h1r : h0r;
      int q = li ? q1 : q0;
      __hip_atomic_store(ring + ((q * 4 + col) << 12) + (rowg << 6) + b * 4 + (u >> 1),
                         v, __ATOMIC_RELAXED, AGENT_SCOPE);
    }
  };

  auto gbar = [&](u32 target) {
    __syncthreads();
    if (tid == 0) {
      __hip_atomic_fetch_add(gcnt, 1u, __ATOMIC_RELEASE, AGENT_SCOPE);
      int it = 0;
      while (__hip_atomic_load(gcnt, __ATOMIC_RELAXED, AGENT_SCOPE) < target && ++it < SPIN_CAP) {}
      (void)__hip_atomic_load(gcnt, __ATOMIC_ACQUIRE, AGENT_SCOPE);
    }
    __syncthreads();
  };

  // lane's weight row: n = (wid&1)*16 + m; gate = n>>3, unit = n&7
  const int nl = (wid & 1) * 16 + m;
  const int gw = ((nl >> 3) << 9) + rowg * 8 + (nl & 7);

  short8 wb[32];

  // ================= encoder weights -> VGPRs =================
  if (wid < 2) {
    #pragma unroll
    for (int t = 0; t < 4; ++t)  wb[t]      = ldw(eWih0, 128, gw, t * 32);
    #pragma unroll
    for (int t = 0; t < 16; ++t) wb[4 + t]  = ldw(eWhh0, 512, gw, t * 32);
  } else {
    #pragma unroll
    for (int t = 0; t < 16; ++t) wb[t]      = ldw(eWih1, 512, gw, t * 32);
    #pragma unroll
    for (int t = 0; t < 16; ++t) wb[16 + t] = ldw(eWhh1, 512, gw, t * 32);
  }
  if (tid < 64) {
    int li = tid >> 5, n = tid & 31;
    int g = ((n >> 3) << 9) + rowg * 8 + (n & 7);
    sBias[li * 32 + n] = li ? (ebi1[g] + ebh1[g]) : (ebi0[g] + ebh0[g]);
  }
  sC[tid] = 0.f;
  __syncthreads();

  // ================= encoder scan (lag-1 pipelined, barrier-free) =====
  for (int s = 0; s <= 1024; ++s) {
    const bool L0 = (s < 1024), L1 = (s >= 1);
    // T14 split: issue x loads BEFORE the poll (latency overlaps poll round),
    // convert + LDS-write after the poll completes.
    float4 xf0, xf1;
    const int xb = tid >> 4, xseg = tid & 15;
    if (L0) {
      const float* p = x + (size_t)(col * 16 + xb) * 131072 + (size_t)s * 128 + xseg * 8;
      xf0 = *(const float4*)p; xf1 = *(const float4*)(p + 4);
    }
    stage_slot((s + 2) % 3, (s + 1) % 3, true, s >= 1);   // h0[s-1], h1[s-2]
    if (L0) {
      uint4 v;
      v.x = (u32)f2bf(xf0.x) | ((u32)f2bf(xf0.y) << 16);
      v.y = (u32)f2bf(xf0.z) | ((u32)f2bf(xf0.w) << 16);
      v.z = (u32)f2bf(xf1.x) | ((u32)f2bf(xf1.y) << 16);
      v.w = (u32)f2bf(xf1.z) | ((u32)f2bf(xf1.w) << 16);
      *(uint4*)(sX + xb * 136 + xseg * 8) = v;
    }
    __syncthreads();
    clears(s);

    f32x4 acc = {0.f, 0.f, 0.f, 0.f};
    if (wid < 2) {
      if (L0) {
        #pragma unroll
        for (int t = 0; t < 4; ++t) {
          short8 a = *(const short8*)(sX + m * 136 + t * 32 + qo);
          acc = __builtin_amdgcn_mfma_f32_16x16x32_bf16(a, wb[t], acc, 0, 0, 0);
        }
        #pragma unroll
        for (int t = 0; t < 16; ++t) {
          short8 a = *(const short8*)(sH0 + m * 520 + t * 32 + qo);
          acc = __builtin_amdgcn_mfma_f32_16x16x32_bf16(a, wb[4 + t], acc, 0, 0, 0);
        }
      }
    } else {
      if (L1) {
        #pragma unroll
        for (int t = 0; t < 16; ++t) {
          short8 a = *(const short8*)(sH0 + m * 520 + t * 32 + qo);
          acc = __builtin_amdgcn_mfma_f32_16x16x32_bf16(a, wb[t], acc, 0, 0, 0);
        }
        #pragma unroll
        for (int t = 0; t < 16; ++t) {
          short8 a = *(const short8*)(sH1 + m * 520 + t * 32 + qo);
          acc = __builtin_amdgcn_mfma_f32_16x16x32_bf16(a, wb[16 + t], acc, 0, 0, 0);
        }
      }
    }
    {
      bool wact = (wid < 2) ? L0 : L1;
      if (wact) {
        int mb = (lane >> 4) * 4;
        #pragma unroll
        for (int r = 0; r < 4; ++r) sP[wid * 256 + (mb + r) * 16 + m] = acc[r];
      }
    }
    __syncthreads();                       // drains clears (vmcnt0) + SP visible
    act_store(L0, L1, s % 3, (s + 2) % 3); // h0[s] -> q s%3, h1[s-1] -> q (s-1)%3
  }

  // ================= latent: z = h1[1023] @ tlW^T + tlb ====================
  {  // h1[1023] is in h1 ring q0 (stored at slot 1024)
    const u32* b1 = h1r + ((0 * 4 + col) << 12) + tid;
    u32 v1[16];
    int it = 0; bool ok = false;
    while (!ok && it++ < POLL_CAP) {
      ok = true;
      #pragma unroll
      for (int i = 0; i < 16; ++i) {
        v1[i] = __hip_atomic_load(b1 + i * 256, __ATOMIC_RELAXED, AGENT_SCOPE);
        ok &= (v1[i] != SENT);
      }
    }
    u32* dH1 = (u32*)sH1;
    #pragma unroll
    for (int i = 0; i < 16; ++i) {
      int g = i * 256 + tid;
      dH1[((g >> 2) & 15) * 260 + (g >> 6) * 4 + (g & 3)] = v1[i];
    }
  }
  __syncthreads();
  if (tid < 16) {
    int b = tid;
    float acc = tlb[rowg];
    for (int kk = 0; kk < 512; kk += 8) {
      short8 hv = *(const short8*)(sH1 + b * 520 + kk);
      #pragma unroll
      for (int j = 0; j < 8; ++j) acc += bf2f((u16)hv[j]) * tlW[rowg * 512 + kk + j];
    }
    int gb = col * 16 + b;
    __hip_atomic_store((u32*)zbuf + gb * 64 + rowg, __float_as_uint(acc),
                       __ATOMIC_RELAXED, AGENT_SCOPE);
    out[8388608 + gb * 64 + rowg] = acc;
  }
  gbar(256);        // z visible everywhere; all WGs done with encoder rings

  // ---- reset rings for decoder: all q SENT (own blocks) ----
  if (tid < 64) {
    #pragma unroll
    for (int q = 0; q < 3; ++q) {
      __hip_atomic_store(h0r + ((q * 4 + col) << 12) + (rowg << 6) + tid,
                         SENT, __ATOMIC_RELAXED, AGENT_SCOPE);
      __hip_atomic_store(h1r + ((q * 4 + col) << 12) + (rowg << 6) + tid,
                         SENT, __ATOMIC_RELAXED, AGENT_SCOPE);
    }
  }
  wait_vm0();       // clears committed before init_h data stores below

  // ================= decoder weights -> VGPRs ==============================
  short8 rcw[16];   // recon B-frags: opW rows rowg*2+nl (wave 0, lanes nl<2)
  {
    const short8 rz = {0, 0, 0, 0, 0, 0, 0, 0};
    #pragma unroll
    for (int t = 0; t < 16; ++t) rcw[t] = rz;
  }
  if (wid < 2) {
    #pragma unroll
    for (int t = 0; t < 16; ++t) wb[t] = ldw(dWhh0, 512, gw, t * 32);
    if (wid == 0 && nl < 2) {
      #pragma unroll
      for (int t = 0; t < 16; ++t) rcw[t] = ldw(opW, 512, rowg * 2 + nl, t * 32);
    }
  } else {
    #pragma unroll
    for (int t = 0; t < 16; ++t) wb[t]      = ldw(dWih1, 512, gw, t * 32);
    #pragma unroll
    for (int t = 0; t < 16; ++t) wb[16 + t] = ldw(dWhh1, 512, gw, t * 32);
  }
  if (tid < 64) {
    int li = tid >> 5, n = tid & 31;
    int g = ((n >> 3) << 9) + rowg * 8 + (n & 7);
    sBias[li * 32 + n] = li ? (dbi1[g] + dbh1[g]) : (dbi0[g] + dbh0[g]);
  }
  if (tid < 2) sOPB[tid] = opb[rowg * 2 + tid];
  sC[tid] = 0.f;

  // ---- init_h = tanh(z @ lhW^T + lhb), torch flat view (L,B,H):
  // init_h[l][bb][h] = M[l*32 + bb/2][(bb&1)*512 + h]; store as h[-1] into q2.
  {
    int ri = tid >> 4, kk = (tid & 15) * 4;
    int zr = ((ri >> 3) << 5) + 8 * col + (ri & 7);
    #pragma unroll
    for (int j = 0; j < 4; ++j)
      sZ[ri * 64 + kk + j] = __uint_as_float(
          __hip_atomic_load((u32*)zbuf + zr * 64 + kk + j, __ATOMIC_RELAXED, AGENT_SCOPE));
  }
  __syncthreads();
  {
    int li = tid >> 7, hh = (tid >> 4) & 7, qb = (tid >> 3) & 1, u = tid & 7;
    int cc = qb * 512 + rowg * 8 + u;
    int bl = 2 * hh + qb;
    float acc2 = lhb[cc];
    const float* lw = lhW + (size_t)cc * 64;
    #pragma unroll 8
    for (int k = 0; k < 64; ++k) acc2 += sZ[(li * 8 + hh) * 64 + k] * lw[k];
    u16 hb = f2bf(tanha(acc2));
    u32 other = __shfl_xor((u32)hb, 1);
    if (!(u & 1)) {
      u32 v = (u32)hb | (other << 16);
      u32* ring = li ? h1r : h0r;
      __hip_atomic_store(ring + ((2 * 4 + col) << 12) + (rowg << 6) + bl * 4 + (u >> 1),
                         v, __ATOMIC_RELAXED, AGENT_SCOPE);
    }
  }
  gbar(512);        // ring resets globally visible before any decoder poll

  // ================= decoder scan + fused MFMA recon =======================
  for (int s = 0; s <= 1025; ++s) {
    const bool L0 = (s < 1024), L1 = (s >= 1 && s <= 1024), RC = (s >= 2);
    stage_slot((s + 2) % 3, (s + 1) % 3, s <= 1024, s >= 1);
    __syncthreads();
    clears(s);

    f32x4 acc  = {0.f, 0.f, 0.f, 0.f};
    f32x4 racc = {0.f, 0.f, 0.f, 0.f};
    if (wid < 2) {
      if (L0) {
        #pragma unroll
        for (int t = 0; t < 16; ++t) {
          short8 a = *(const short8*)(sH0 + m * 520 + t * 32 + qo);
          acc = __builtin_amdgcn_mfma_f32_16x16x32_bf16(a, wb[t], acc, 0, 0, 0);
        }
      }
    } else {
      if (L1) {
        #pragma unroll
        for (int t = 0; t < 16; ++t) {
          short8 a = *(const short8*)(sH0 + m * 520 + t * 32 + qo);
          acc = __builtin_amdgcn_mfma_f32_16x16x32_bf16(a, wb[t], acc, 0, 0, 0);
        }
        #pragma unroll
        for (int t = 0; t < 16; ++t) {
          short8 a = *(const short8*)(sH1 + m * 520 + t * 32 + qo);
          acc = __builtin_amdgcn_mfma_f32_16x16x32_bf16(a, wb[16 + t], acc, 0, 0, 0);
        }
      }
    }
    // recon[t=s-2] = sigmoid(h1dec[s-2] @ opW^T + opb) as MFMA on wave 0:
    // A rows = batches (sH1, already staged for the L1 input), B cols 0,1 =
    // opW rows rowg*2+{0,1} (rcw), cols 2..15 zero. Rides in wid0's slack
    // (16 L0 MFMAs + 16 RC MFMAs == wid2/3's 32).
    if (wid == 0 && RC) {
      #pragma unroll
      for (int t = 0; t < 16; ++t) {
        short8 a = *(const short8*)(sH1 + m * 520 + t * 32 + qo);
        racc = __builtin_amdgcn_mfma_f32_16x16x32_bf16(a, rcw[t], racc, 0, 0, 0);
      }
    }
    {
      bool wact = (wid < 2) ? L0 : L1;
      if (wact) {
        int mb = (lane >> 4) * 4;
        #pragma unroll
        for (int r = 0; r < 4; ++r) sP[wid * 256 + (mb + r) * 16 + m] = acc[r];
      }
    }
    __syncthreads();
    act_store(L0, L1, s % 3, (s + 2) % 3);
    // RC epilogue after act_store: C[row=b][col=dd] on lanes m<2 (dd=m,
    // b=(lane>>4)*4+r). Stores drain overlapped with the next poll.
    if (wid == 0 && RC && m < 2) {
      #pragma unroll
      for (int r = 0; r < 4; ++r) {
        int b = (lane >> 4) * 4 + r;
        out[(size_t)(col * 16 + b) * 131072 + (size_t)(s - 2) * 128 + rowg * 2 + m]
            = sigm(racc[r] + sOPB[m]);
      }
    }
  }
}

extern "C" void kernel_launch(void* const* d_in, const int* in_sizes, int n_in,
                              void* d_out, int out_size, void* d_ws, size_t ws_size,
                              hipStream_t stream) {
  (void)in_sizes; (void)n_in; (void)out_size; (void)ws_size;
  char* ws = (char*)d_ws;
  // control + zbuf
  hipMemsetAsync(ws, 0, 32768, stream);
  // h0 ring: q0,q1 = SENT (not yet produced), q2 = 0.0 data (h0[-1] = 0)
  hipMemsetAsync(ws + 32768, 0xFF, 131072, stream);
  hipMemsetAsync(ws + 163840, 0x00, 65536, stream);
  // h1 ring: q0,q1 = SENT, q2 = 0.0 data (h1[-1] = 0)
  hipMemsetAsync(ws + 229376, 0xFF, 131072, stream);
  hipMemsetAsync(ws + 360448, 0x00, 65536, stream);
  lstm_ae_kernel<<<dim3(256), dim3(256), 0, stream>>>(
      (const float*)d_in[0],
      (const float*)d_in[1],  (const float*)d_in[2],
      (const float*)d_in[3],  (const float*)d_in[4],
      (const float*)d_in[5],  (const float*)d_in[6],
      (const float*)d_in[7],  (const float*)d_in[8],
      (const float*)d_in[10],
      (const float*)d_in[11], (const float*)d_in[12],
      (const float*)d_in[13], (const float*)d_in[14],
      (const float*)d_in[15], (const float*)d_in[16],
      (const float*)d_in[17], (const float*)d_in[18],
      (const float*)d_in[19], (const float*)d_in[20],
      (const float*)d_in[21], (const float*)d_in[22],
      (float*)d_out, (char*)d_ws);
}